// Round 1
// 1881.572 us; speedup vs baseline: 1.6393x; 1.6393x over previous
//
#include <hip/hip_runtime.h>
#include <hip/hip_bf16.h>
#include <cstdint>
#include <cstddef>

#define DEVI __device__ __forceinline__

typedef __bf16 v8bf __attribute__((ext_vector_type(8)));
typedef float  v4f  __attribute__((ext_vector_type(4)));
using u16 = unsigned short;

// problem dims
constexpr int kB = 4096, kT = 16, kH = 256, kF = 256, kZ = 128, kP = 10, kPrev = 5;
constexpr int kRows = 16;      // rows per block; grid = 4096/16 = 256 (one block per CU)
constexpr int kThreads = 512;  // 8 waves -> 2 waves/SIMD

// ---- workspace layout (bf16 elements): transposed weights ONLY (~2.82 MB) ----
constexpr size_t OFF_WzT = 0;                                  // Wz: n=1024, K=128
constexpr size_t OFF_WhT = OFF_WzT + (size_t)1024 * 128;       // Wh: n=1024, K=256
constexpr size_t OFF_WyT = OFF_WhT + (size_t)1024 * 256;       // Wy: n=1024, K=256
constexpr size_t OFF_UT  = OFF_WyT + (size_t)1024 * 256;       // U : n=1024, K=256
constexpr size_t OFF_W1T = OFF_UT  + (size_t)1024 * 256;       // W1: n=256, K=256
constexpr size_t OFF_W2T = OFF_W1T + (size_t)256 * 256;
constexpr size_t OFF_W3T = OFF_W2T + (size_t)256 * 256;
constexpr size_t OFF_W4T = OFF_W3T + (size_t)256 * 256;        // W4: n=128, K=1024
constexpr size_t OFF_W5T = OFF_W4T + (size_t)128 * 1024;       // W5: n=128, K=128
constexpr size_t OFF_W6T = OFF_W5T + (size_t)128 * 128;
constexpr size_t OFF_W7T = OFF_W6T + (size_t)128 * 128;        // W7: n=128, K=768
constexpr size_t OFF_W8T = OFF_W7T + (size_t)128 * 768;
constexpr size_t OFF_W9T = OFF_W8T + (size_t)128 * 128;
constexpr size_t OFF_WEND= OFF_W9T + (size_t)128 * 128;

// ---- output layout (elements, FLOAT32) ----
constexpr size_t O_YS   = 0;
constexpr size_t O_MPO  = O_YS   + (size_t)kB * kP * kF;
constexpr size_t O_LVPO = O_MPO  + (size_t)kB * kP * kZ;
constexpr size_t O_MPR  = O_LVPO + (size_t)kB * kP * kZ;
constexpr size_t O_LVPR = O_MPR  + (size_t)kB * kP * kZ;
constexpr size_t O_ZPO  = O_LVPR + (size_t)kB * kP * kZ;
constexpr size_t O_ZPR  = O_ZPO  + (size_t)kP * kB * kZ;
constexpr size_t O_PROB = O_ZPR  + (size_t)kP * kB * kZ;

DEVI float bf2f(u16 u) { return __uint_as_float(((unsigned)u) << 16); }
DEVI u16 f2bf(float f) {
    unsigned x = __float_as_uint(f);
    return (u16)((x + 0x7fffu + ((x >> 16) & 1u)) >> 16);   // RNE
}
DEVI unsigned pk2(float lo, float hi) { return (unsigned)f2bf(lo) | ((unsigned)f2bf(hi) << 16); }
DEVI float upk(unsigned u, int hi) { return __uint_as_float(hi ? (u & 0xffff0000u) : (u << 16)); }
DEVI float sigf(float x) { x = fminf(fmaxf(x, -40.f), 40.f); return 1.f / (1.f + __expf(-x)); }
DEVI float tanhf_(float x) {
    x = fminf(fmaxf(x, -15.f), 15.f);
    float e = __expf(2.f * x);
    return (e - 1.f) / (e + 1.f);
}
DEVI v8bf ld8(const u16* p) { return *(const v8bf*)p; }
DEVI void nts(float v, float* p) { __builtin_nontemporal_store(v, p); }
DEVI float ntl(const float* p) { return __builtin_nontemporal_load(p); }

template <int NTL>
DEVI void zacc(v4f (&a)[NTL]) {
#pragma unroll
    for (int t = 0; t < NTL; ++t) a[t] = v4f{0, 0, 0, 0};
}

// C[m][n] += A[m][k] * W[k][n]. A in LDS row-major [16][K+pad] bf16.
// WT transposed bf16 in global: row n holds K elems (leading dim wtK).
// A frag: lane holds A[m=ln][k=q*8+j]; B frag: B[k=q*8+j][n=ln];
// C/D: col=ln, row=q*4+r (16x16x32 bf16 MFMA, layout verified previously).
// All NTL B-fragments for a k-block are loaded BEFORE the MFMAs so the
// VMEM queue holds NTL independent loads in flight.
template <int K, int NTL, class NFN>
DEVI void gemm_acc(v4f (&acc)[NTL], const u16* A, int astr,
                   const u16* __restrict__ WT, int wtK, int wtOff,
                   NFN nf, int ln, int q) {
    const u16* A0 = A + ln * astr + q * 8;
    const u16* B0 = WT + (size_t)ln * wtK + (size_t)wtOff + q * 8;
#pragma unroll
    for (int k0 = 0; k0 < K; k0 += 32) {
        v8bf b[NTL];
#pragma unroll
        for (int t = 0; t < NTL; ++t)
            b[t] = ld8(B0 + (size_t)nf(t) * wtK + k0);
        v8bf a0 = ld8(A0 + k0);
#pragma unroll
        for (int t = 0; t < NTL; ++t)
            acc[t] = __builtin_amdgcn_mfma_f32_16x16x32_bf16(a0, b[t], acc[t], 0, 0, 0);
    }
}

// relu epilogue -> LDS (bf16), biases from registers
template <int NTL, class NFN>
DEVI void epi_relu(v4f (&acc)[NTL], const float (&bias)[NTL],
                   u16* s_dst, int dstr, NFN nf, int ln, int q) {
#pragma unroll
    for (int t = 0; t < NTL; ++t)
#pragma unroll
        for (int r = 0; r < 4; ++r) {
            int rl = q * 4 + r, n = nf(t) + ln;
            s_dst[rl * dstr + n] = f2bf(fmaxf(acc[t][r] + bias[t], 0.f));
        }
}

// ---------------- weight transpose: f32 W[k][n] -> bf16 WT[n][k] ----------------
__global__ void transpose_w(const float* __restrict__ Wl, const float* __restrict__ U,
                            const float* __restrict__ W1, const float* __restrict__ W2,
                            const float* __restrict__ W3, const float* __restrict__ W4,
                            const float* __restrict__ W5, const float* __restrict__ W6,
                            const float* __restrict__ W7, const float* __restrict__ W8,
                            const float* __restrict__ W9, u16* __restrict__ ws) {
    size_t e = (size_t)blockIdx.x * blockDim.x + threadIdx.x;
    auto tp = [&](size_t eo, size_t dst, const float* src, int K, int srcN, int rowOff) {
        size_t n = eo / (size_t)K;
        size_t k = eo - n * (size_t)K;
        ws[dst + eo] = f2bf(src[(size_t)(rowOff + k) * srcN + n]);
    };
    if      (e < OFF_WhT) tp(e - OFF_WzT, OFF_WzT, Wl, 128, 1024, 0);
    else if (e < OFF_WyT) tp(e - OFF_WhT, OFF_WhT, Wl, 256, 1024, 128);
    else if (e < OFF_UT)  tp(e - OFF_WyT, OFF_WyT, Wl, 256, 1024, 384);
    else if (e < OFF_W1T) tp(e - OFF_UT,  OFF_UT,  U,  256, 1024, 0);
    else if (e < OFF_W2T) tp(e - OFF_W1T, OFF_W1T, W1, 256, 256, 0);
    else if (e < OFF_W3T) tp(e - OFF_W2T, OFF_W2T, W2, 256, 256, 0);
    else if (e < OFF_W4T) tp(e - OFF_W3T, OFF_W3T, W3, 256, 256, 0);
    else if (e < OFF_W5T) tp(e - OFF_W4T, OFF_W4T, W4, 1024, 128, 0);
    else if (e < OFF_W6T) tp(e - OFF_W5T, OFF_W5T, W5, 128, 128, 0);
    else if (e < OFF_W7T) tp(e - OFF_W6T, OFF_W6T, W6, 128, 128, 0);
    else if (e < OFF_W8T) tp(e - OFF_W7T, OFF_W7T, W7, 768, 128, 0);
    else if (e < OFF_W9T) tp(e - OFF_W8T, OFF_W8T, W8, 128, 128, 0);
    else if (e < OFF_WEND)tp(e - OFF_W9T, OFF_W9T, W9, 128, 128, 0);
}

// ---------------- fused recurrent kernel: 16 rows/block, 8 waves, 10 steps ----------------
__global__ __launch_bounds__(512, 1) void fused_vrnn(
    const float* __restrict__ g_hi, const float* __restrict__ g_t,
    const float* __restrict__ g_npo, const float* __restrict__ g_npr,
    const float* __restrict__ b_lstm, const float* __restrict__ b1,
    const float* __restrict__ b2, const float* __restrict__ b3,
    const float* __restrict__ b4, const float* __restrict__ b5,
    const float* __restrict__ b6, const float* __restrict__ b7,
    const float* __restrict__ b8, const float* __restrict__ b9,
    const float* __restrict__ g_alpha, const float* __restrict__ g_beta,
    const float* __restrict__ g_base,
    const u16* __restrict__ ws, float* __restrict__ out) {
    __shared__ __align__(16) u16 s_h[kRows][kH + 8];
    __shared__ __align__(16) u16 s_zj[kRows][kZ + 8];
    __shared__ __align__(16) u16 s_yp[2][kRows][kF + 8];
    __shared__ __align__(16) u16 s_hraw[kRows][kH + 8];
    __shared__ __align__(16) u16 s_t1[kRows][kF + 8];
    __shared__ __align__(16) u16 s_t2[kRows][kF + 8];
    __shared__ __align__(16) u16 s_hz[kRows][kZ + 8];
    __shared__ __align__(16) u16 s_hzp[kRows][kZ + 8];
    __shared__ float s_lam[kP][kRows];

    const int tid = threadIdx.x;
    const int w = tid >> 6, lane = tid & 63, ln = lane & 15, q = lane >> 4;
    const int r0 = blockIdx.x * kRows;

    // zero recurrent state, stage h_i (f32 -> bf16) into s_hraw
    for (int i = tid; i < kRows * (kH + 8); i += kThreads) (&s_h[0][0])[i] = 0;
    for (int i = tid; i < kRows * (kZ + 8); i += kThreads) (&s_zj[0][0])[i] = 0;
    for (int i = tid; i < 2 * kRows * (kF + 8); i += kThreads) (&s_yp[0][0][0])[i] = 0;
    for (int i = tid; i < kRows * kH; i += kThreads) {
        int r = i >> 8, c = i & (kH - 1);
        s_hraw[r][c] = f2bf(g_hi[(size_t)(r0 + r) * kH + c]);
    }

    // Hawkes lam/prob per row (threads 0..15, one row each), f32 exact
    if (tid < kRows) {
        const float alpha = g_alpha[0], beta = g_beta[0], base = g_base[0];
        float tv[kT];
#pragma unroll
        for (int i = 0; i < kT; ++i) tv[i] = g_t[(size_t)(r0 + tid) * kT + i];
#pragma unroll 1
        for (int j = 0; j < kP; ++j) {
            int cti = kPrev + j;
            float ct = tv[cti], last = tv[cti - 1];
            float tk = 0.f, td3 = 0.f;
            for (int i = 0; i < cti; ++i) {
                tk += __expf(beta * (tv[i] - ct));
                td3 += __expf(beta * (tv[i] - last));
            }
            float lam = base + alpha * tk;
            float prob = lam * __expf((last - ct) * base + (alpha / beta) * (tk - td3));
            s_lam[j][tid] = lam;
            nts(prob, &out[O_PROB + (size_t)j * kB + (size_t)(r0 + tid)]);
        }
    }

    // col-ownership maps: 8 waves
    auto nfg = [&](int t) { return ((t >> 1) << 8) + (w << 5) + ((t & 1) << 4); }; // gates: 4 gates x 2 tiles
    auto nf4 = [&](int t) { return (w << 5) + (t << 4); };                          // N=256: 2 tiles
    auto nf2 = [&](int)   { return (w << 4); };                                     // N=128: 1 tile

    // hoist biases into registers (per-thread cols are step-invariant)
    float rbl[4][2];
#pragma unroll
    for (int g = 0; g < 4; ++g)
#pragma unroll
        for (int s = 0; s < 2; ++s) rbl[g][s] = b_lstm[(g << 8) + (w << 5) + (s << 4) + ln];
    float rb1[2], rb2[2], rb3[2];
#pragma unroll
    for (int t = 0; t < 2; ++t) {
        rb1[t] = b1[nf4(t) + ln];
        rb2[t] = b2[nf4(t) + ln];
        rb3[t] = b3[nf4(t) + ln];
    }
    const int n2 = (w << 4) + ln;
    const float rb4 = b4[n2], rb5 = b5[n2], rb6 = b6[n2], rb7 = b7[n2], rb8 = b8[n2], rb9 = b9[n2];

    __syncthreads();

    // ---- step-invariant h_i partials, kept in registers (packed bf16 pairs) ----
    unsigned ghi_p[8][2];  // h_i @ W_lstm[h_i rows] (cols via nfg)
    unsigned h4i_p[2];     // h_i @ W4[0:256]
    unsigned h7i_p[2];     // h_i @ W7[0:256]
    {
        v4f acc[8]; zacc(acc);
        gemm_acc<256, 8>(acc, &s_hraw[0][0], kH + 8, ws + OFF_WhT, 256, 0, nfg, ln, q);
#pragma unroll
        for (int t = 0; t < 8; ++t) {
            ghi_p[t][0] = pk2(acc[t][0], acc[t][1]);
            ghi_p[t][1] = pk2(acc[t][2], acc[t][3]);
        }
    }
    {
        v4f acc[1]; zacc(acc);
        gemm_acc<256, 1>(acc, &s_hraw[0][0], kH + 8, ws + OFF_W4T, 1024, 0, nf2, ln, q);
        h4i_p[0] = pk2(acc[0][0], acc[0][1]);
        h4i_p[1] = pk2(acc[0][2], acc[0][3]);
    }
    {
        v4f acc[1]; zacc(acc);
        gemm_acc<256, 1>(acc, &s_hraw[0][0], kH + 8, ws + OFF_W7T, 768, 0, nf2, ln, q);
        h7i_p[0] = pk2(acc[0][0], acc[0][1]);
        h7i_p[1] = pk2(acc[0][2], acc[0][3]);
    }
    __syncthreads();

    // LSTM cell state in registers: c_st[s][r] <-> col w*32+s*16+ln, row q*4+r
    float c_st[2][4];
#pragma unroll
    for (int s = 0; s < 2; ++s)
#pragma unroll
        for (int r = 0; r < 4; ++r) c_st[s][r] = 0.f;

#pragma unroll 1
    for (int j = 0; j < kP; ++j) {
        const int cur = j & 1, nxt = cur ^ 1;

        // ---- LSTM gates: zj@Wz + y_prev@Wy + h@U (+ ghi + b) ----
        {
            v4f acc[8]; zacc(acc);
            gemm_acc<128, 8>(acc, &s_zj[0][0], kZ + 8, ws + OFF_WzT, 128, 0, nfg, ln, q);
            gemm_acc<256, 8>(acc, &s_yp[cur][0][0], kF + 8, ws + OFF_WyT, 256, 0, nfg, ln, q);
            gemm_acc<256, 8>(acc, &s_h[0][0], kH + 8, ws + OFF_UT, 256, 0, nfg, ln, q);
            __syncthreads();  // all waves done reading s_h before overwriting
#pragma unroll
            for (int s = 0; s < 2; ++s)
#pragma unroll
                for (int r = 0; r < 4; ++r) {
                    const int rl = q * 4 + r;
                    const int nc = (w << 5) + (s << 4) + ln;
                    float gi = acc[s][r]     + upk(ghi_p[s][r >> 1], r & 1)     + rbl[0][s];
                    float gf = acc[2 + s][r] + upk(ghi_p[2 + s][r >> 1], r & 1) + rbl[1][s];
                    float gg = acc[4 + s][r] + upk(ghi_p[4 + s][r >> 1], r & 1) + rbl[2][s];
                    float go = acc[6 + s][r] + upk(ghi_p[6 + s][r >> 1], r & 1) + rbl[3][s];
                    float cs = c_st[s][r];
                    cs = sigf(gf) * cs + sigf(gi) * tanhf_(gg);
                    float hr = sigf(go) * tanhf_(cs);
                    c_st[s][r] = cs;
                    float lamv = s_lam[j][rl];
                    s_hraw[rl][nc] = f2bf(hr);
                    s_h[rl][nc] = f2bf(lamv * hr);
                }
        }
        __syncthreads();

        v4f a4[1]; zacc(a4);  // W4 accumulator, persists through phases B..D

        // ---- Phase A: y1 = relu(hraw@W1) || hz_p gemms (W7: hraw + y_prev parts) ----
        {
            v4f a1[2]; zacc(a1);
            v4f a7[1]; zacc(a7);
            gemm_acc<256, 2>(a1, &s_hraw[0][0], kH + 8, ws + OFF_W1T, 256, 0, nf4, ln, q);
            gemm_acc<256, 1>(a7, &s_hraw[0][0], kH + 8, ws + OFF_W7T, 768, 256, nf2, ln, q);
            gemm_acc<256, 1>(a7, &s_yp[cur][0][0], kF + 8, ws + OFF_W7T, 768, 512, nf2, ln, q);
            epi_relu<2>(a1, rb1, &s_t1[0][0], kF + 8, nf4, ln, q);
#pragma unroll
            for (int r = 0; r < 4; ++r) {
                float v = a7[0][r] + upk(h7i_p[r >> 1], r & 1) + rb7;
                s_hzp[q * 4 + r][n2] = f2bf(fmaxf(v, 0.f));
            }
        }
        __syncthreads();

        // ---- Phase B: y2 || prior mean/logv (W8/W9) || W4 partials (hraw, y_prev) ----
        {
            v4f a2[2]; zacc(a2);
            v4f a8[1], a9[1]; zacc(a8); zacc(a9);
            gemm_acc<256, 2>(a2, &s_t1[0][0], kF + 8, ws + OFF_W2T, 256, 0, nf4, ln, q);
            gemm_acc<128, 1>(a8, &s_hzp[0][0], kZ + 8, ws + OFF_W8T, 128, 0, nf2, ln, q);
            gemm_acc<128, 1>(a9, &s_hzp[0][0], kZ + 8, ws + OFF_W9T, 128, 0, nf2, ln, q);
            gemm_acc<256, 1>(a4, &s_hraw[0][0], kH + 8, ws + OFF_W4T, 1024, 256, nf2, ln, q);
            gemm_acc<256, 1>(a4, &s_yp[cur][0][0], kF + 8, ws + OFF_W4T, 1024, 768, nf2, ln, q);
            epi_relu<2>(a2, rb2, &s_t2[0][0], kF + 8, nf4, ln, q);
#pragma unroll
            for (int r = 0; r < 4; ++r) {
                int rl = q * 4 + r;
                size_t grow = (size_t)(r0 + rl);
                float mp = fmaxf(a8[0][r] + rb8, 0.f);
                float lp = fmaxf(a9[0][r] + rb9, 0.f);
                nts(mp, &out[O_MPR + (grow * kP + j) * kZ + n2]);
                nts(lp, &out[O_LVPR + (grow * kP + j) * kZ + n2]);
                float nz = ntl(&g_npr[((size_t)j * kB + grow) * kZ + n2]);
                nts(mp + nz * __expf(0.5f * lp), &out[O_ZPR + ((size_t)j * kB + grow) * kZ + n2]);
            }
        }
        __syncthreads();

        // ---- Phase C: y = relu(t2@W3), store ys + next y_prev ----
        {
            v4f a3[2]; zacc(a3);
            gemm_acc<256, 2>(a3, &s_t2[0][0], kF + 8, ws + OFF_W3T, 256, 0, nf4, ln, q);
#pragma unroll
            for (int t = 0; t < 2; ++t)
#pragma unroll
                for (int r = 0; r < 4; ++r) {
                    int rl = q * 4 + r, n = nf4(t) + ln;
                    size_t grow = (size_t)(r0 + rl);
                    float yv = fmaxf(a3[t][r] + rb3[t], 0.f);
                    s_yp[nxt][rl][n] = f2bf(yv);
                    nts(yv, &out[O_YS + (grow * kP + j) * kF + n]);
                }
        }
        __syncthreads();

        // ---- Phase D: W4 y-part + hz epilogue ----
        {
            gemm_acc<256, 1>(a4, &s_yp[nxt][0][0], kF + 8, ws + OFF_W4T, 1024, 512, nf2, ln, q);
#pragma unroll
            for (int r = 0; r < 4; ++r) {
                float v = a4[0][r] + upk(h4i_p[r >> 1], r & 1) + rb4;
                s_hz[q * 4 + r][n2] = f2bf(fmaxf(v, 0.f));
            }
        }
        __syncthreads();

        // ---- Phase E: posterior mean/logv (W5/W6), z_j ----
        {
            v4f a5[1], a6[1]; zacc(a5); zacc(a6);
            gemm_acc<128, 1>(a5, &s_hz[0][0], kZ + 8, ws + OFF_W5T, 128, 0, nf2, ln, q);
            gemm_acc<128, 1>(a6, &s_hz[0][0], kZ + 8, ws + OFF_W6T, 128, 0, nf2, ln, q);
#pragma unroll
            for (int r = 0; r < 4; ++r) {
                int rl = q * 4 + r;
                size_t grow = (size_t)(r0 + rl);
                float mn = fmaxf(a5[0][r] + rb5, 0.f);
                float lv = fmaxf(a6[0][r] + rb6, 0.f);
                nts(mn, &out[O_MPO + (grow * kP + j) * kZ + n2]);
                nts(lv, &out[O_LVPO + (grow * kP + j) * kZ + n2]);
                float nz = ntl(&g_npo[((size_t)j * kB + grow) * kZ + n2]);
                float zj = mn + nz * __expf(0.5f * lv);
                s_zj[rl][n2] = f2bf(zj);
                nts(zj, &out[O_ZPO + ((size_t)j * kB + grow) * kZ + n2]);
            }
        }
        __syncthreads();
    }
}

extern "C" void kernel_launch(void* const* d_in, const int* in_sizes, int n_in,
                              void* d_out, int out_size, void* d_ws, size_t ws_size,
                              hipStream_t stream) {
    const float* hi  = (const float*)d_in[0];
    const float* it  = (const float*)d_in[1];
    const float* npo = (const float*)d_in[2];
    const float* npr = (const float*)d_in[3];
    const float* Wl  = (const float*)d_in[4];
    const float* U   = (const float*)d_in[5];
    const float* bl  = (const float*)d_in[6];
    const float* W1  = (const float*)d_in[7];
    const float* b1  = (const float*)d_in[8];
    const float* W2  = (const float*)d_in[9];
    const float* b2  = (const float*)d_in[10];
    const float* W3  = (const float*)d_in[11];
    const float* b3  = (const float*)d_in[12];
    const float* W4  = (const float*)d_in[13];
    const float* b4  = (const float*)d_in[14];
    const float* W5  = (const float*)d_in[15];
    const float* b5  = (const float*)d_in[16];
    const float* W6  = (const float*)d_in[17];
    const float* b6  = (const float*)d_in[18];
    const float* W7  = (const float*)d_in[19];
    const float* b7  = (const float*)d_in[20];
    const float* W8  = (const float*)d_in[21];
    const float* b8  = (const float*)d_in[22];
    const float* W9  = (const float*)d_in[23];
    const float* b9  = (const float*)d_in[24];
    const float* al  = (const float*)d_in[25];
    const float* be  = (const float*)d_in[26];
    const float* ba  = (const float*)d_in[27];
    u16* ws   = (u16*)d_ws;
    float* out = (float*)d_out;

    const unsigned tblocks = (unsigned)((OFF_WEND + 255) / 256);
    transpose_w<<<dim3(tblocks), dim3(256), 0, stream>>>(Wl, U, W1, W2, W3, W4, W5, W6, W7, W8, W9, ws);
    fused_vrnn<<<dim3(kB / kRows), dim3(kThreads), 0, stream>>>(
        hi, it, npo, npr, bl, b1, b2, b3, b4, b5, b6, b7, b8, b9, al, be, ba, ws, out);
}

// Round 2
// 1373.033 us; speedup vs baseline: 2.2465x; 1.3704x over previous
//
#include <hip/hip_runtime.h>
#include <hip/hip_bf16.h>
#include <cstdint>
#include <cstddef>

#define DEVI __device__ __forceinline__

typedef __bf16 v8bf __attribute__((ext_vector_type(8)));
typedef float  v4f  __attribute__((ext_vector_type(4)));
using u16 = unsigned short;

// problem dims
constexpr int kB = 4096, kT = 16, kH = 256, kF = 256, kZ = 128, kP = 10, kPrev = 5;
constexpr int kRows = 16;       // rows per block; grid = 4096/16 = 256 (one block per CU)
constexpr int kThreads = 1024;  // 16 waves -> 4 waves/SIMD

// ---- workspace layout (bf16 elements): transposed weights ONLY (~2.82 MB) ----
constexpr size_t OFF_WzT = 0;                                  // Wz: n=1024, K=128
constexpr size_t OFF_WhT = OFF_WzT + (size_t)1024 * 128;       // Wh: n=1024, K=256
constexpr size_t OFF_WyT = OFF_WhT + (size_t)1024 * 256;       // Wy: n=1024, K=256
constexpr size_t OFF_UT  = OFF_WyT + (size_t)1024 * 256;       // U : n=1024, K=256
constexpr size_t OFF_W1T = OFF_UT  + (size_t)1024 * 256;       // W1: n=256, K=256
constexpr size_t OFF_W2T = OFF_W1T + (size_t)256 * 256;
constexpr size_t OFF_W3T = OFF_W2T + (size_t)256 * 256;
constexpr size_t OFF_W4T = OFF_W3T + (size_t)256 * 256;        // W4: n=128, K=1024
constexpr size_t OFF_W5T = OFF_W4T + (size_t)128 * 1024;       // W5: n=128, K=128
constexpr size_t OFF_W6T = OFF_W5T + (size_t)128 * 128;
constexpr size_t OFF_W7T = OFF_W6T + (size_t)128 * 128;        // W7: n=128, K=768
constexpr size_t OFF_W8T = OFF_W7T + (size_t)128 * 768;
constexpr size_t OFF_W9T = OFF_W8T + (size_t)128 * 128;
constexpr size_t OFF_WEND= OFF_W9T + (size_t)128 * 128;

// ---- output layout (elements, FLOAT32) ----
constexpr size_t O_YS   = 0;
constexpr size_t O_MPO  = O_YS   + (size_t)kB * kP * kF;
constexpr size_t O_LVPO = O_MPO  + (size_t)kB * kP * kZ;
constexpr size_t O_MPR  = O_LVPO + (size_t)kB * kP * kZ;
constexpr size_t O_LVPR = O_MPR  + (size_t)kB * kP * kZ;
constexpr size_t O_ZPO  = O_LVPR + (size_t)kB * kP * kZ;
constexpr size_t O_ZPR  = O_ZPO  + (size_t)kP * kB * kZ;
constexpr size_t O_PROB = O_ZPR  + (size_t)kP * kB * kZ;

DEVI float bf2f(u16 u) { return __uint_as_float(((unsigned)u) << 16); }
DEVI u16 f2bf(float f) {
    unsigned x = __float_as_uint(f);
    return (u16)((x + 0x7fffu + ((x >> 16) & 1u)) >> 16);   // RNE
}
DEVI unsigned pk2(float lo, float hi) { return (unsigned)f2bf(lo) | ((unsigned)f2bf(hi) << 16); }
DEVI float upk(unsigned u, int hi) { return __uint_as_float(hi ? (u & 0xffff0000u) : (u << 16)); }
DEVI float sigf(float x) { x = fminf(fmaxf(x, -40.f), 40.f); return 1.f / (1.f + __expf(-x)); }
DEVI float tanhf_(float x) {
    x = fminf(fmaxf(x, -15.f), 15.f);
    float e = __expf(2.f * x);
    return (e - 1.f) / (e + 1.f);
}
DEVI v8bf ld8(const u16* p) { return *(const v8bf*)p; }
DEVI void nts(float v, float* p) { __builtin_nontemporal_store(v, p); }
DEVI float ntl(const float* p) { return __builtin_nontemporal_load(p); }

template <int NTL>
DEVI void zacc(v4f (&a)[NTL]) {
#pragma unroll
    for (int t = 0; t < NTL; ++t) a[t] = v4f{0, 0, 0, 0};
}

// C[m][n] += A[m][k] * W[k][n]. A in LDS row-major [16][K+pad] bf16.
// WT transposed bf16 in global: row n holds wtK elems.
// A frag: lane holds A[m=ln][k=q*8+j]; B frag: B[k=q*8+j][n=ln];
// C/D: col=ln, row=q*4+r (16x16x32 bf16 MFMA, layout verified / passing).
template <int K, int NTL, class NFN>
DEVI void gemm_acc(v4f (&acc)[NTL], const u16* A, int astr,
                   const u16* __restrict__ WT, int wtK, int wtOff,
                   NFN nf, int ln, int q) {
    const u16* A0 = A + ln * astr + q * 8;
    const u16* B0 = WT + (size_t)ln * wtK + (size_t)wtOff + q * 8;
#pragma unroll
    for (int k0 = 0; k0 < K; k0 += 32) {
        v8bf b[NTL];
#pragma unroll
        for (int t = 0; t < NTL; ++t)
            b[t] = ld8(B0 + (size_t)nf(t) * wtK + k0);
        v8bf a0 = ld8(A0 + k0);
#pragma unroll
        for (int t = 0; t < NTL; ++t)
            acc[t] = __builtin_amdgcn_mfma_f32_16x16x32_bf16(a0, b[t], acc[t], 0, 0, 0);
    }
}

// dual GEMM, K=128, one N-tile each from two weight matrices (same A)
DEVI void gemm2_128(v4f& aA, v4f& aB, const u16* A, int astr,
                    const u16* __restrict__ BA, const u16* __restrict__ BB,
                    int ln, int q) {
    const u16* A0 = A + ln * astr + q * 8;
    const u16* pa = BA + (size_t)ln * 128 + q * 8;
    const u16* pb = BB + (size_t)ln * 128 + q * 8;
#pragma unroll
    for (int k0 = 0; k0 < 128; k0 += 32) {
        v8bf b1 = ld8(pa + k0);
        v8bf b2 = ld8(pb + k0);
        v8bf av = ld8(A0 + k0);
        aA = __builtin_amdgcn_mfma_f32_16x16x32_bf16(av, b1, aA, 0, 0, 0);
        aB = __builtin_amdgcn_mfma_f32_16x16x32_bf16(av, b2, aB, 0, 0, 0);
    }
}

// relu epilogue -> LDS (bf16), biases from registers
template <int NTL, class NFN>
DEVI void epi_relu(v4f (&acc)[NTL], const float (&bias)[NTL],
                   u16* s_dst, int dstr, NFN nf, int ln, int q) {
#pragma unroll
    for (int t = 0; t < NTL; ++t)
#pragma unroll
        for (int r = 0; r < 4; ++r) {
            int rl = q * 4 + r, n = nf(t) + ln;
            s_dst[rl * dstr + n] = f2bf(fmaxf(acc[t][r] + bias[t], 0.f));
        }
}

// ---------------- weight transpose: f32 W[k][n] -> bf16 WT[n][k] ----------------
__global__ void transpose_w(const float* __restrict__ Wl, const float* __restrict__ U,
                            const float* __restrict__ W1, const float* __restrict__ W2,
                            const float* __restrict__ W3, const float* __restrict__ W4,
                            const float* __restrict__ W5, const float* __restrict__ W6,
                            const float* __restrict__ W7, const float* __restrict__ W8,
                            const float* __restrict__ W9, u16* __restrict__ ws) {
    size_t e = (size_t)blockIdx.x * blockDim.x + threadIdx.x;
    auto tp = [&](size_t eo, size_t dst, const float* src, int K, int srcN, int rowOff) {
        size_t n = eo / (size_t)K;
        size_t k = eo - n * (size_t)K;
        ws[dst + eo] = f2bf(src[(size_t)(rowOff + k) * srcN + n]);
    };
    if      (e < OFF_WhT) tp(e - OFF_WzT, OFF_WzT, Wl, 128, 1024, 0);
    else if (e < OFF_WyT) tp(e - OFF_WhT, OFF_WhT, Wl, 256, 1024, 128);
    else if (e < OFF_UT)  tp(e - OFF_WyT, OFF_WyT, Wl, 256, 1024, 384);
    else if (e < OFF_W1T) tp(e - OFF_UT,  OFF_UT,  U,  256, 1024, 0);
    else if (e < OFF_W2T) tp(e - OFF_W1T, OFF_W1T, W1, 256, 256, 0);
    else if (e < OFF_W3T) tp(e - OFF_W2T, OFF_W2T, W2, 256, 256, 0);
    else if (e < OFF_W4T) tp(e - OFF_W3T, OFF_W3T, W3, 256, 256, 0);
    else if (e < OFF_W5T) tp(e - OFF_W4T, OFF_W4T, W4, 1024, 128, 0);
    else if (e < OFF_W6T) tp(e - OFF_W5T, OFF_W5T, W5, 128, 128, 0);
    else if (e < OFF_W7T) tp(e - OFF_W6T, OFF_W6T, W6, 128, 128, 0);
    else if (e < OFF_W8T) tp(e - OFF_W7T, OFF_W7T, W7, 768, 128, 0);
    else if (e < OFF_W9T) tp(e - OFF_W8T, OFF_W8T, W8, 128, 128, 0);
    else if (e < OFF_WEND)tp(e - OFF_W9T, OFF_W9T, W9, 128, 128, 0);
}

// ---------------- fused recurrent kernel: 16 rows/block, 16 waves, 10 steps ----------------
__global__ __launch_bounds__(1024, 1) void fused_vrnn(
    const float* __restrict__ g_hi, const float* __restrict__ g_t,
    const float* __restrict__ g_npo, const float* __restrict__ g_npr,
    const float* __restrict__ b_lstm, const float* __restrict__ b1,
    const float* __restrict__ b2, const float* __restrict__ b3,
    const float* __restrict__ b4, const float* __restrict__ b5,
    const float* __restrict__ b6, const float* __restrict__ b7,
    const float* __restrict__ b8, const float* __restrict__ b9,
    const float* __restrict__ g_alpha, const float* __restrict__ g_beta,
    const float* __restrict__ g_base,
    const u16* __restrict__ ws, float* __restrict__ out) {
    __shared__ __align__(16) u16 s_h[kRows][kH + 8];
    __shared__ __align__(16) u16 s_zj[kRows][kZ + 8];
    __shared__ __align__(16) u16 s_yp[2][kRows][kF + 8];
    __shared__ __align__(16) u16 s_hraw[kRows][kH + 8];
    __shared__ __align__(16) u16 s_t1[kRows][kF + 8];
    __shared__ __align__(16) u16 s_t2[kRows][kF + 8];
    __shared__ __align__(16) u16 s_hz[kRows][kZ + 8];
    __shared__ __align__(16) u16 s_hzp[kRows][kZ + 8];
    __shared__ float s_lam[kP][kRows];

    const int tid = threadIdx.x;
    const int w = tid >> 6, lane = tid & 63, ln = lane & 15, q = lane >> 4;
    const int wl = w & 7;
    const bool lo = (w < 8);
    const int r0 = blockIdx.x * kRows;

    // zero recurrent state, stage h_i (f32 -> bf16) into s_hraw
    for (int i = tid; i < kRows * (kH + 8); i += kThreads) (&s_h[0][0])[i] = 0;
    for (int i = tid; i < kRows * (kZ + 8); i += kThreads) (&s_zj[0][0])[i] = 0;
    for (int i = tid; i < 2 * kRows * (kF + 8); i += kThreads) (&s_yp[0][0][0])[i] = 0;
    for (int i = tid; i < kRows * kH; i += kThreads) {
        int r = i >> 8, c = i & (kH - 1);
        s_hraw[r][c] = f2bf(g_hi[(size_t)(r0 + r) * kH + c]);
    }

    // Hawkes lam/prob per row (threads 0..15, one row each), f32 exact
    if (tid < kRows) {
        const float alpha = g_alpha[0], beta = g_beta[0], base = g_base[0];
        float tv[kT];
#pragma unroll
        for (int i = 0; i < kT; ++i) tv[i] = g_t[(size_t)(r0 + tid) * kT + i];
#pragma unroll 1
        for (int j = 0; j < kP; ++j) {
            int cti = kPrev + j;
            float ct = tv[cti], last = tv[cti - 1];
            float tk = 0.f, td3 = 0.f;
            for (int i = 0; i < cti; ++i) {
                tk += __expf(beta * (tv[i] - ct));
                td3 += __expf(beta * (tv[i] - last));
            }
            float lam = base + alpha * tk;
            float prob = lam * __expf((last - ct) * base + (alpha / beta) * (tk - td3));
            s_lam[j][tid] = lam;
            nts(prob, &out[O_PROB + (size_t)j * kB + (size_t)(r0 + tid)]);
        }
    }

    // col-ownership maps: 16 waves
    auto nfg  = [&](int t) { return (t << 8) + (w << 4); };          // gates: tile w of each of 4 gates
    auto nf12 = [&](int t) { return (w + (t << 3)) << 4; };          // waves 0-7: N=256 tiles {w, w+8}
    auto nf3  = [&](int)   { return w << 4; };                       // N=256: tile w (all 16 waves)
    auto nfh  = [&](int)   { return wl << 4; };                      // N=128: tile wl (role waves)

    // hoist biases into registers (per-thread cols are step-invariant)
    float rbl[4];
#pragma unroll
    for (int g = 0; g < 4; ++g) rbl[g] = b_lstm[(g << 8) + (w << 4) + ln];
    float rb1[2] = {0.f, 0.f}, rb2[2] = {0.f, 0.f};
    if (lo) {
#pragma unroll
        for (int t = 0; t < 2; ++t) {
            rb1[t] = b1[nf12(t) + ln];
            rb2[t] = b2[nf12(t) + ln];
        }
    }
    const float rb3v = b3[(w << 4) + ln];
    const int nhl = (wl << 4) + ln;       // col within N=128 role tiles
    float rb4 = 0.f, rb5 = 0.f, rb6 = 0.f, rb7 = 0.f, rb8 = 0.f, rb9 = 0.f;
    if (lo) { rb5 = b5[nhl]; rb6 = b6[nhl]; }
    else    { rb4 = b4[nhl]; rb7 = b7[nhl]; rb8 = b8[nhl]; rb9 = b9[nhl]; }

    __syncthreads();

    // ---- step-invariant h_i partials, kept in registers (packed bf16 pairs) ----
    unsigned ghi_p[4][2];                 // h_i @ W_lstm[h_i rows] (4 gate tiles)
    unsigned h4i_p[2] = {0, 0};           // waves 8-15: h_i @ W4[0:256]
    unsigned h7i_p[2] = {0, 0};           // waves 8-15: h_i @ W7[0:256]
    {
        v4f acc[4]; zacc(acc);
        gemm_acc<256, 4>(acc, &s_hraw[0][0], kH + 8, ws + OFF_WhT, 256, 0, nfg, ln, q);
#pragma unroll
        for (int t = 0; t < 4; ++t) {
            ghi_p[t][0] = pk2(acc[t][0], acc[t][1]);
            ghi_p[t][1] = pk2(acc[t][2], acc[t][3]);
        }
    }
    if (!lo) {
        v4f a[1]; zacc(a);
        gemm_acc<256, 1>(a, &s_hraw[0][0], kH + 8, ws + OFF_W4T, 1024, 0, nfh, ln, q);
        h4i_p[0] = pk2(a[0][0], a[0][1]);
        h4i_p[1] = pk2(a[0][2], a[0][3]);
        v4f b[1]; zacc(b);
        gemm_acc<256, 1>(b, &s_hraw[0][0], kH + 8, ws + OFF_W7T, 768, 0, nfh, ln, q);
        h7i_p[0] = pk2(b[0][0], b[0][1]);
        h7i_p[1] = pk2(b[0][2], b[0][3]);
    }
    __syncthreads();

    // LSTM cell state in registers: c_st[r] <-> col w*16+ln, row q*4+r
    float c_st[4] = {0.f, 0.f, 0.f, 0.f};

#pragma unroll 1
    for (int j = 0; j < kP; ++j) {
        const int cur = j & 1, nxt = cur ^ 1;

        // ---- LSTM gates: zj@Wz + y_prev@Wy + h@U (+ ghi + b) ----
        {
            v4f acc[4]; zacc(acc);
            gemm_acc<128, 4>(acc, &s_zj[0][0], kZ + 8, ws + OFF_WzT, 128, 0, nfg, ln, q);
            gemm_acc<256, 4>(acc, &s_yp[cur][0][0], kF + 8, ws + OFF_WyT, 256, 0, nfg, ln, q);
            gemm_acc<256, 4>(acc, &s_h[0][0], kH + 8, ws + OFF_UT, 256, 0, nfg, ln, q);
            __syncthreads();  // all waves done reading s_h before overwriting
            const int nc = (w << 4) + ln;
#pragma unroll
            for (int r = 0; r < 4; ++r) {
                const int rl = q * 4 + r;
                float gi = acc[0][r] + upk(ghi_p[0][r >> 1], r & 1) + rbl[0];
                float gf = acc[1][r] + upk(ghi_p[1][r >> 1], r & 1) + rbl[1];
                float gg = acc[2][r] + upk(ghi_p[2][r >> 1], r & 1) + rbl[2];
                float go = acc[3][r] + upk(ghi_p[3][r >> 1], r & 1) + rbl[3];
                float cs = c_st[r];
                cs = sigf(gf) * cs + sigf(gi) * tanhf_(gg);
                float hr = sigf(go) * tanhf_(cs);
                c_st[r] = cs;
                float lamv = s_lam[j][rl];
                s_hraw[rl][nc] = f2bf(hr);
                s_h[rl][nc] = f2bf(lamv * hr);
            }
        }
        __syncthreads();

        v4f a4[1]; zacc(a4);  // W4 accumulator (waves 8-15), persists B..D

        // ---- Phase A: waves 0-7: y1 = relu(hraw@W1) | waves 8-15: hz_p (W7) ----
        if (lo) {
            v4f a1[2]; zacc(a1);
            gemm_acc<256, 2>(a1, &s_hraw[0][0], kH + 8, ws + OFF_W1T, 256, 0, nf12, ln, q);
            epi_relu<2>(a1, rb1, &s_t1[0][0], kF + 8, nf12, ln, q);
        } else {
            v4f a7[1]; zacc(a7);
            gemm_acc<256, 1>(a7, &s_hraw[0][0], kH + 8, ws + OFF_W7T, 768, 256, nfh, ln, q);
            gemm_acc<256, 1>(a7, &s_yp[cur][0][0], kF + 8, ws + OFF_W7T, 768, 512, nfh, ln, q);
#pragma unroll
            for (int r = 0; r < 4; ++r) {
                float v = a7[0][r] + upk(h7i_p[r >> 1], r & 1) + rb7;
                s_hzp[q * 4 + r][nhl] = f2bf(fmaxf(v, 0.f));
            }
        }
        __syncthreads();

        // ---- Phase B: waves 0-7: y2 (W2) | waves 8-15: W4 partials (hraw, y_prev) ----
        if (lo) {
            v4f a2[2]; zacc(a2);
            gemm_acc<256, 2>(a2, &s_t1[0][0], kF + 8, ws + OFF_W2T, 256, 0, nf12, ln, q);
            epi_relu<2>(a2, rb2, &s_t2[0][0], kF + 8, nf12, ln, q);
        } else {
            gemm_acc<256, 1>(a4, &s_hraw[0][0], kH + 8, ws + OFF_W4T, 1024, 256, nfh, ln, q);
            gemm_acc<256, 1>(a4, &s_yp[cur][0][0], kF + 8, ws + OFF_W4T, 1024, 768, nfh, ln, q);
        }
        __syncthreads();

        // ---- Phase C: all: y = relu(t2@W3) | waves 8-15 also: prior W8/W9 + stores ----
        {
            v4f a3[1]; zacc(a3);
            v4f a8 = v4f{0, 0, 0, 0}, a9 = v4f{0, 0, 0, 0};
            gemm_acc<256, 1>(a3, &s_t2[0][0], kF + 8, ws + OFF_W3T, 256, 0, nf3, ln, q);
            if (!lo)
                gemm2_128(a8, a9, &s_hzp[0][0], kZ + 8,
                          ws + OFF_W8T + (size_t)(wl << 4) * 128,
                          ws + OFF_W9T + (size_t)(wl << 4) * 128, ln, q);
            const int n3 = (w << 4) + ln;
#pragma unroll
            for (int r = 0; r < 4; ++r) {
                int rl = q * 4 + r;
                size_t grow = (size_t)(r0 + rl);
                float yv = fmaxf(a3[0][r] + rb3v, 0.f);
                s_yp[nxt][rl][n3] = f2bf(yv);
                nts(yv, &out[O_YS + (grow * kP + j) * kF + n3]);
            }
            if (!lo) {
#pragma unroll
                for (int r = 0; r < 4; ++r) {
                    int rl = q * 4 + r;
                    size_t grow = (size_t)(r0 + rl);
                    float mp = fmaxf(a8[r] + rb8, 0.f);
                    float lp = fmaxf(a9[r] + rb9, 0.f);
                    nts(mp, &out[O_MPR + (grow * kP + j) * kZ + nhl]);
                    nts(lp, &out[O_LVPR + (grow * kP + j) * kZ + nhl]);
                    float nz = ntl(&g_npr[((size_t)j * kB + grow) * kZ + nhl]);
                    nts(mp + nz * __expf(0.5f * lp),
                        &out[O_ZPR + ((size_t)j * kB + grow) * kZ + nhl]);
                }
            }
        }
        __syncthreads();

        // ---- Phase D: waves 8-15: W4 y-part + hz epilogue ----
        if (!lo) {
            gemm_acc<256, 1>(a4, &s_yp[nxt][0][0], kF + 8, ws + OFF_W4T, 1024, 512, nfh, ln, q);
#pragma unroll
            for (int r = 0; r < 4; ++r) {
                float v = a4[0][r] + upk(h4i_p[r >> 1], r & 1) + rb4;
                s_hz[q * 4 + r][nhl] = f2bf(fmaxf(v, 0.f));
            }
        }
        __syncthreads();

        // ---- Phase E: waves 0-7: posterior W5/W6, z_j ----
        if (lo) {
            v4f a5 = v4f{0, 0, 0, 0}, a6 = v4f{0, 0, 0, 0};
            gemm2_128(a5, a6, &s_hz[0][0], kZ + 8,
                      ws + OFF_W5T + (size_t)(w << 4) * 128,
                      ws + OFF_W6T + (size_t)(w << 4) * 128, ln, q);
#pragma unroll
            for (int r = 0; r < 4; ++r) {
                int rl = q * 4 + r;
                size_t grow = (size_t)(r0 + rl);
                float mn = fmaxf(a5[r] + rb5, 0.f);
                float lv = fmaxf(a6[r] + rb6, 0.f);
                nts(mn, &out[O_MPO + (grow * kP + j) * kZ + nhl]);
                nts(lv, &out[O_LVPO + (grow * kP + j) * kZ + nhl]);
                float nz = ntl(&g_npo[((size_t)j * kB + grow) * kZ + nhl]);
                float zj = mn + nz * __expf(0.5f * lv);
                s_zj[rl][nhl] = f2bf(zj);
                nts(zj, &out[O_ZPO + ((size_t)j * kB + grow) * kZ + nhl]);
            }
        }
        __syncthreads();
    }
}

extern "C" void kernel_launch(void* const* d_in, const int* in_sizes, int n_in,
                              void* d_out, int out_size, void* d_ws, size_t ws_size,
                              hipStream_t stream) {
    const float* hi  = (const float*)d_in[0];
    const float* it  = (const float*)d_in[1];
    const float* npo = (const float*)d_in[2];
    const float* npr = (const float*)d_in[3];
    const float* Wl  = (const float*)d_in[4];
    const float* U   = (const float*)d_in[5];
    const float* bl  = (const float*)d_in[6];
    const float* W1  = (const float*)d_in[7];
    const float* b1  = (const float*)d_in[8];
    const float* W2  = (const float*)d_in[9];
    const float* b2  = (const float*)d_in[10];
    const float* W3  = (const float*)d_in[11];
    const float* b3  = (const float*)d_in[12];
    const float* W4  = (const float*)d_in[13];
    const float* b4  = (const float*)d_in[14];
    const float* W5  = (const float*)d_in[15];
    const float* b5  = (const float*)d_in[16];
    const float* W6  = (const float*)d_in[17];
    const float* b6  = (const float*)d_in[18];
    const float* W7  = (const float*)d_in[19];
    const float* b7  = (const float*)d_in[20];
    const float* W8  = (const float*)d_in[21];
    const float* b8  = (const float*)d_in[22];
    const float* W9  = (const float*)d_in[23];
    const float* b9  = (const float*)d_in[24];
    const float* al  = (const float*)d_in[25];
    const float* be  = (const float*)d_in[26];
    const float* ba  = (const float*)d_in[27];
    u16* ws   = (u16*)d_ws;
    float* out = (float*)d_out;

    const unsigned tblocks = (unsigned)((OFF_WEND + 255) / 256);
    transpose_w<<<dim3(tblocks), dim3(256), 0, stream>>>(Wl, U, W1, W2, W3, W4, W5, W6, W7, W8, W9, ws);
    fused_vrnn<<<dim3(kB / kRows), dim3(kThreads), 0, stream>>>(
        hi, it, npo, npr, bl, b1, b2, b3, b4, b5, b6, b7, b8, b9, al, be, ba, ws, out);
}